// Round 4
// baseline (483.323 us; speedup 1.0000x reference)
//
#include <hip/hip_runtime.h>

#define S_SCALE 30.0f
#define COS_M 0.8775825618903728f
#define SIN_M 0.479425538604203f
#define TH_C (-0.8775825618903728f)
#define MM_C 0.2397127693021015f

#define BD 512
#define DD 512
#define CC 100000
#define NCB 1563            // ceil(100000/64)

typedef __bf16 bf16x8 __attribute__((ext_vector_type(8)));
typedef float  f32x4  __attribute__((ext_vector_type(4)));

// ---------------- Kernel 1: concat + normalize -> k-tiled bf16 At[16][512][32];
// label-column cosine/phi; zero sums[512]. ----------------
__global__ __launch_bounds__(256) void k_prep(const float* __restrict__ img,
                                              const float* __restrict__ prof,
                                              const float* __restrict__ W,
                                              const int* __restrict__ lab,
                                              __bf16* __restrict__ At,
                                              float* __restrict__ sphi,
                                              float* __restrict__ scos,
                                              float* __restrict__ sums) {
    const int row = blockIdx.x;
    const int t = threadIdx.x;
    const float* src = (row < 256) ? (img + (size_t)row * DD) : (prof + (size_t)(row - 256) * DD);
    float x0 = src[t], x1 = src[t + 256];
    float s = x0 * x0 + x1 * x1;
    for (int o = 1; o < 64; o <<= 1) s += __shfl_xor(s, o);
    __shared__ float ws4[4];
    if ((t & 63) == 0) ws4[t >> 6] = s;
    __syncthreads();
    float r = rsqrtf(ws4[0] + ws4[1] + ws4[2] + ws4[3]);
    __bf16 a0 = (__bf16)(x0 * r), a1 = (__bf16)(x1 * r);
    // k-tiled: (row, d) -> At[(d>>5)*16384 + row*32 + (d&31)]
    At[(size_t)(t >> 5) * (BD * 32) + row * 32 + (t & 31)]         = a0;
    At[(size_t)((t + 256) >> 5) * (BD * 32) + row * 32 + (t & 31)] = a1;

    const int c = lab[row & 255];
    float w0 = (float)(__bf16)W[(size_t)c * DD + t];
    float w1 = (float)(__bf16)W[(size_t)c * DD + t + 256];
    float dot = (float)a0 * w0 + (float)a1 * w1;
    float wsq = w0 * w0 + w1 * w1;
    for (int o = 1; o < 64; o <<= 1) { dot += __shfl_xor(dot, o); wsq += __shfl_xor(wsq, o); }
    __shared__ float sd[4], sw[4];
    if ((t & 63) == 0) { sd[t >> 6] = dot; sw[t >> 6] = wsq; }
    __syncthreads();
    if (t == 0) {
        float D = sd[0] + sd[1] + sd[2] + sd[3];
        float Q = sw[0] + sw[1] + sw[2] + sw[3];
        float cs = D * rsqrtf(Q);
        float sn = sqrtf(fmaxf(0.f, fminf(1.f, 1.f - cs * cs)));
        float phi = cs * COS_M - sn * SIN_M;
        if (!(cs > TH_C)) phi = cs - MM_C;
        sphi[row] = S_SCALE * phi;
        scos[row] = S_SCALE * cs;
        sums[row] = 0.f;
    }
}

// ---------------- Kernel 2: barrier-free, LDS-free MFMA GEMM ----------------
// 4 waves/block; wave w computes rows [w*128, w*128+128) x 64 cols.
// A fragments loaded directly global->reg from k-tiled At (L2-resident, 512 KB).
// B loaded global->reg fp32 with 1-tile register prefetch; cvt->bf16 + sumsq in-loop.
// No __syncthreads, no manual s_waitcnt: per-register vmcnt keeps prefetch in flight.
__global__ __launch_bounds__(256, 2) void k_gemm(const __bf16* __restrict__ At,
                                                 const float* __restrict__ W,
                                                 float* __restrict__ sums) {
    const int t = threadIdx.x;
    const int cb = blockIdx.x;
    const int wave = t >> 6, lane = t & 63, q = lane >> 4, m16 = lane & 15;

    // B pointers: frag j -> col cb*64 + j*16 + m16, k-base q*8
    const float* wb[4];
    bool val[4];
    #pragma unroll
    for (int j = 0; j < 4; ++j) {
        int c = cb * 64 + j * 16 + m16;
        val[j] = (c < CC);
        wb[j] = W + (size_t)(val[j] ? c : 0) * DD + q * 8;
    }
    // A fragment base for this lane: rows wave*128 + i*16 + m16, k-chunk q*8
    const __bf16* ab = At + (wave * 128 + m16) * 32 + q * 8;

    f32x4 acc[8][4] = {};
    float sq[4] = {0.f, 0.f, 0.f, 0.f};

    // prologue: B(0) raw in flight
    float4 braw[4][2];
    #pragma unroll
    for (int j = 0; j < 4; ++j) {
        braw[j][0] = *(const float4*)(wb[j]);
        braw[j][1] = *(const float4*)(wb[j] + 4);
    }

    #pragma unroll
    for (int kt = 0; kt < 16; ++kt) {
        // A fragments for tile kt (L2) — issued before any waits
        bf16x8 af[8];
        #pragma unroll
        for (int i = 0; i < 8; ++i)
            af[i] = *(const bf16x8*)(ab + (size_t)kt * (BD * 32) + i * (16 * 32));

        // prefetch B(kt+1) — stays in flight across cvt + MFMA of tile kt
        float4 bnext[4][2];
        if (kt < 15) {
            #pragma unroll
            for (int j = 0; j < 4; ++j) {
                bnext[j][0] = *(const float4*)(wb[j] + (kt + 1) * 32);
                bnext[j][1] = *(const float4*)(wb[j] + (kt + 1) * 32 + 4);
            }
        }

        // per-j: convert B(kt) then 8 MFMAs (keeps live bf16 frags minimal)
        #pragma unroll
        for (int j = 0; j < 4; ++j) {
            bf16x8 bc;
            const float* f = (const float*)&braw[j][0];
            #pragma unroll
            for (int e = 0; e < 8; ++e) {
                __bf16 b = (__bf16)f[e];
                float fb = (float)b;
                sq[j] += fb * fb;
                bc[e] = b;
            }
            #pragma unroll
            for (int i = 0; i < 8; ++i)
                acc[i][j] = __builtin_amdgcn_mfma_f32_16x16x32_bf16(af[i], bc, acc[i][j], 0, 0, 0);
        }

        if (kt < 15) {
            #pragma unroll
            for (int j = 0; j < 4; ++j) { braw[j][0] = bnext[j][0]; braw[j][1] = bnext[j][1]; }
        }
    }

    // column sumsq: each lane has partial over its q-slice (k = q*8..+8 per tile)
    #pragma unroll
    for (int j = 0; j < 4; ++j) {
        sq[j] += __shfl_xor(sq[j], 16);
        sq[j] += __shfl_xor(sq[j], 32);
    }
    float inv[4];
    #pragma unroll
    for (int j = 0; j < 4; ++j) inv[j] = rsqrtf(sq[j]) * S_SCALE;

    // epilogue: per-row partial sum of exp(S*cosine) -> atomicAdd into sums[512]
    #pragma unroll
    for (int i = 0; i < 8; ++i) {
        #pragma unroll
        for (int r = 0; r < 4; ++r) {
            float e = 0.f;
            #pragma unroll
            for (int j = 0; j < 4; ++j)
                if (val[j]) e += __expf(acc[i][j][r] * inv[j]);
            e += __shfl_xor(e, 1);
            e += __shfl_xor(e, 2);
            e += __shfl_xor(e, 4);
            e += __shfl_xor(e, 8);
            if (m16 == 0) {
                int row = wave * 128 + i * 16 + q * 4 + r;
                atomicAdd(&sums[row], e);
            }
        }
    }
}

// ---------------- Kernel 3: final logsumexp + label correction + mean ----------------
__global__ __launch_bounds__(256) void k_final(const float* __restrict__ sums,
                                               const float* __restrict__ sphi,
                                               const float* __restrict__ scos,
                                               float* __restrict__ out) {
    const int t = threadIdx.x;
    float acc = 0.f;
    #pragma unroll
    for (int h = 0; h < 2; ++h) {
        int row = t + h * 256;
        float lse = logf(sums[row]);
        float sp = sphi[row], sc = scos[row];
        float corr = log1pf(__expf(sp - lse) - __expf(sc - lse));
        acc += lse + corr - sp;
    }
    for (int o = 1; o < 64; o <<= 1) acc += __shfl_xor(acc, o);
    __shared__ float ws4[4];
    if ((t & 63) == 0) ws4[t >> 6] = acc;
    __syncthreads();
    if (t == 0) out[0] = (ws4[0] + ws4[1] + ws4[2] + ws4[3]) * (1.0f / 512.0f);
}

extern "C" void kernel_launch(void* const* d_in, const int* in_sizes, int n_in,
                              void* d_out, int out_size, void* d_ws, size_t ws_size,
                              hipStream_t stream) {
    const float* img  = (const float*)d_in[0];
    const float* prof = (const float*)d_in[1];
    const float* W    = (const float*)d_in[2];
    const int*   lab  = (const int*)d_in[3];

    char* ws = (char*)d_ws;
    __bf16* At   = (__bf16*)ws;                 // 524288 B (k-tiled)
    float* sphi  = (float*)(ws + 524288);       // 2048 B
    float* scos  = (float*)(ws + 526336);       // 2048 B
    float* sums  = (float*)(ws + 528384);       // 2048 B

    k_prep<<<BD, 256, 0, stream>>>(img, prof, W, lab, At, sphi, scos, sums);
    k_gemm<<<NCB, 256, 0, stream>>>(At, W, sums);
    k_final<<<1, 256, 0, stream>>>(sums, sphi, scos, (float*)d_out);
}

// Round 5
// 473.262 us; speedup vs baseline: 1.0213x; 1.0213x over previous
//
#include <hip/hip_runtime.h>

#define S_SCALE 30.0f
#define COS_M 0.8775825618903728f
#define SIN_M 0.479425538604203f
#define TH_C (-0.8775825618903728f)
#define MM_C 0.2397127693021015f

#define BD 512
#define DD 512
#define CC 100000
#define NCB 1563            // ceil(100000/64)

typedef __bf16 bf16x8 __attribute__((ext_vector_type(8)));
typedef float  f32x4  __attribute__((ext_vector_type(4)));

// ---------------- Kernel 1: concat + normalize -> k-tiled bf16 At[16][512][32];
// label-column cosine/phi; zero sums[512]. ----------------
__global__ __launch_bounds__(256) void k_prep(const float* __restrict__ img,
                                              const float* __restrict__ prof,
                                              const float* __restrict__ W,
                                              const int* __restrict__ lab,
                                              __bf16* __restrict__ At,
                                              float* __restrict__ sphi,
                                              float* __restrict__ scos,
                                              float* __restrict__ sums) {
    const int row = blockIdx.x;
    const int t = threadIdx.x;
    const float* src = (row < 256) ? (img + (size_t)row * DD) : (prof + (size_t)(row - 256) * DD);
    float x0 = src[t], x1 = src[t + 256];
    float s = x0 * x0 + x1 * x1;
    for (int o = 1; o < 64; o <<= 1) s += __shfl_xor(s, o);
    __shared__ float ws4[4];
    if ((t & 63) == 0) ws4[t >> 6] = s;
    __syncthreads();
    float r = rsqrtf(ws4[0] + ws4[1] + ws4[2] + ws4[3]);
    __bf16 a0 = (__bf16)(x0 * r), a1 = (__bf16)(x1 * r);
    // k-tiled: (row, d) -> At[(d>>5)*16384 + row*32 + (d&31)]
    At[(size_t)(t >> 5) * (BD * 32) + row * 32 + (t & 31)]         = a0;
    At[(size_t)((t + 256) >> 5) * (BD * 32) + row * 32 + (t & 31)] = a1;

    const int c = lab[row & 255];
    float w0 = (float)(__bf16)W[(size_t)c * DD + t];
    float w1 = (float)(__bf16)W[(size_t)c * DD + t + 256];
    float dot = (float)a0 * w0 + (float)a1 * w1;
    float wsq = w0 * w0 + w1 * w1;
    for (int o = 1; o < 64; o <<= 1) { dot += __shfl_xor(dot, o); wsq += __shfl_xor(wsq, o); }
    __shared__ float sd[4], sw[4];
    if ((t & 63) == 0) { sd[t >> 6] = dot; sw[t >> 6] = wsq; }
    __syncthreads();
    if (t == 0) {
        float D = sd[0] + sd[1] + sd[2] + sd[3];
        float Q = sw[0] + sw[1] + sw[2] + sw[3];
        float cs = D * rsqrtf(Q);
        float sn = sqrtf(fmaxf(0.f, fminf(1.f, 1.f - cs * cs)));
        float phi = cs * COS_M - sn * SIN_M;
        if (!(cs > TH_C)) phi = cs - MM_C;
        sphi[row] = S_SCALE * phi;
        scos[row] = S_SCALE * cs;
        sums[row] = 0.f;
    }
}

// ---------------- Kernel 2: barrier-free, LDS-free MFMA GEMM, deep pipeline ----------------
// launch_bounds(256,1): 512-reg budget -> no spill (R4's killer). 1 block/CU by design;
// latency hidden by ILP: B (HBM) prefetched 3 tiles deep (4-slot ring), A (L2) 1 deep.
// No __syncthreads / manual waitcnt: per-register vmcnt keeps the pipe in flight.
__global__ __launch_bounds__(256, 1) void k_gemm(const __bf16* __restrict__ At,
                                                 const float* __restrict__ W,
                                                 float* __restrict__ sums) {
    const int t = threadIdx.x;
    const int cb = blockIdx.x;
    const int wave = t >> 6, lane = t & 63, q = lane >> 4, m16 = lane & 15;

    // B pointers: frag j -> col cb*64 + j*16 + m16, k-base q*8
    const float* wb[4];
    bool val[4];
    #pragma unroll
    for (int j = 0; j < 4; ++j) {
        int c = cb * 64 + j * 16 + m16;
        val[j] = (c < CC);
        wb[j] = W + (size_t)(val[j] ? c : 0) * DD + q * 8;
    }
    // A fragment base: rows wave*128 + i*16 + m16, k-chunk q*8; tile stride 16384 elems
    const __bf16* ab = At + (wave * 128 + m16) * 32 + q * 8;

    f32x4 acc[8][4] = {};
    float sq[4] = {0.f, 0.f, 0.f, 0.f};

    bf16x8 af[2][8];        // A double buffer (cur/next)
    float4 bq[4][4][2];     // B 4-slot ring [slot][j][half], 3 slots in flight

    // prologue: A(0); B(0),B(1),B(2)
    #pragma unroll
    for (int i = 0; i < 8; ++i)
        af[0][i] = *(const bf16x8*)(ab + i * (16 * 32));
    #pragma unroll
    for (int p = 0; p < 3; ++p)
        #pragma unroll
        for (int j = 0; j < 4; ++j) {
            bq[p][j][0] = *(const float4*)(wb[j] + p * 32);
            bq[p][j][1] = *(const float4*)(wb[j] + p * 32 + 4);
        }

    #pragma unroll
    for (int kt = 0; kt < 16; ++kt) {
        const int cur = kt & 1;
        // issue A(kt+1) first (L2, consumed next iter; older than B so its wait is cheap)
        if (kt < 15) {
            #pragma unroll
            for (int i = 0; i < 8; ++i)
                af[1 - cur][i] = *(const bf16x8*)(ab + (size_t)(kt + 1) * (BD * 32) + i * (16 * 32));
        }
        // issue B(kt+3) into ring slot (kt+3)&3 (consumed in 3 iters)
        if (kt < 13) {
            const int sl = (kt + 3) & 3;
            #pragma unroll
            for (int j = 0; j < 4; ++j) {
                bq[sl][j][0] = *(const float4*)(wb[j] + (kt + 3) * 32);
                bq[sl][j][1] = *(const float4*)(wb[j] + (kt + 3) * 32 + 4);
            }
        }

        // consume B(kt) from slot kt&3: cvt->bf16 + sumsq, then MFMA burst
        const int cs_ = kt & 3;
        #pragma unroll
        for (int j = 0; j < 4; ++j) {
            bf16x8 bc;
            const float* f = (const float*)&bq[cs_][j][0];
            #pragma unroll
            for (int e = 0; e < 8; ++e) {
                __bf16 b = (__bf16)f[e];
                float fb = (float)b;
                sq[j] += fb * fb;
                bc[e] = b;
            }
            #pragma unroll
            for (int i = 0; i < 8; ++i)
                acc[i][j] = __builtin_amdgcn_mfma_f32_16x16x32_bf16(af[cur][i], bc, acc[i][j], 0, 0, 0);
        }
    }

    // column sumsq: lane partial covers k = q*8..+8 per tile; reduce over q
    #pragma unroll
    for (int j = 0; j < 4; ++j) {
        sq[j] += __shfl_xor(sq[j], 16);
        sq[j] += __shfl_xor(sq[j], 32);
    }
    float inv[4];
    #pragma unroll
    for (int j = 0; j < 4; ++j) inv[j] = rsqrtf(sq[j]) * S_SCALE;

    // epilogue: per-row partial sum of exp(S*cosine) -> atomicAdd into sums[512]
    #pragma unroll
    for (int i = 0; i < 8; ++i) {
        #pragma unroll
        for (int r = 0; r < 4; ++r) {
            float e = 0.f;
            #pragma unroll
            for (int j = 0; j < 4; ++j)
                if (val[j]) e += __expf(acc[i][j][r] * inv[j]);
            e += __shfl_xor(e, 1);
            e += __shfl_xor(e, 2);
            e += __shfl_xor(e, 4);
            e += __shfl_xor(e, 8);
            if (m16 == 0) {
                int row = wave * 128 + i * 16 + q * 4 + r;
                atomicAdd(&sums[row], e);
            }
        }
    }
}

// ---------------- Kernel 3: final logsumexp + label correction + mean ----------------
__global__ __launch_bounds__(256) void k_final(const float* __restrict__ sums,
                                               const float* __restrict__ sphi,
                                               const float* __restrict__ scos,
                                               float* __restrict__ out) {
    const int t = threadIdx.x;
    float acc = 0.f;
    #pragma unroll
    for (int h = 0; h < 2; ++h) {
        int row = t + h * 256;
        float lse = logf(sums[row]);
        float sp = sphi[row], sc = scos[row];
        float corr = log1pf(__expf(sp - lse) - __expf(sc - lse));
        acc += lse + corr - sp;
    }
    for (int o = 1; o < 64; o <<= 1) acc += __shfl_xor(acc, o);
    __shared__ float ws4[4];
    if ((t & 63) == 0) ws4[t >> 6] = acc;
    __syncthreads();
    if (t == 0) out[0] = (ws4[0] + ws4[1] + ws4[2] + ws4[3]) * (1.0f / 512.0f);
}

extern "C" void kernel_launch(void* const* d_in, const int* in_sizes, int n_in,
                              void* d_out, int out_size, void* d_ws, size_t ws_size,
                              hipStream_t stream) {
    const float* img  = (const float*)d_in[0];
    const float* prof = (const float*)d_in[1];
    const float* W    = (const float*)d_in[2];
    const int*   lab  = (const int*)d_in[3];

    char* ws = (char*)d_ws;
    __bf16* At   = (__bf16*)ws;                 // 524288 B (k-tiled)
    float* sphi  = (float*)(ws + 524288);       // 2048 B
    float* scos  = (float*)(ws + 526336);       // 2048 B
    float* sums  = (float*)(ws + 528384);       // 2048 B

    k_prep<<<BD, 256, 0, stream>>>(img, prof, W, lab, At, sphi, scos, sums);
    k_gemm<<<NCB, 256, 0, stream>>>(At, W, sums);
    k_final<<<1, 256, 0, stream>>>(sums, sphi, scos, (float*)d_out);
}

// Round 6
// 462.546 us; speedup vs baseline: 1.0449x; 1.0232x over previous
//
#include <hip/hip_runtime.h>

#define S_SCALE 30.0f
#define COS_M 0.8775825618903728f
#define SIN_M 0.479425538604203f
#define TH_C (-0.8775825618903728f)
#define MM_C 0.2397127693021015f

#define BD 512
#define DD 512
#define CC 100000
#define NCB 1563            // ceil(100000/64)
#define LASTB 1562

typedef __bf16 bf16x8 __attribute__((ext_vector_type(8)));
typedef __bf16 bf16x4 __attribute__((ext_vector_type(4)));
typedef float  f32x4  __attribute__((ext_vector_type(4)));

#define AS1 __attribute__((address_space(1)))
#define AS3 __attribute__((address_space(3)))

// ---------------- Kernel 1: concat + normalize -> k-tiled bf16 At[16][512][32];
// label-column cosine/phi; zero sums[512]. ----------------
__global__ __launch_bounds__(256) void k_prep(const float* __restrict__ img,
                                              const float* __restrict__ prof,
                                              const float* __restrict__ W,
                                              const int* __restrict__ lab,
                                              __bf16* __restrict__ At,
                                              float* __restrict__ sphi,
                                              float* __restrict__ scos,
                                              float* __restrict__ sums) {
    const int row = blockIdx.x;
    const int t = threadIdx.x;
    const float* src = (row < 256) ? (img + (size_t)row * DD) : (prof + (size_t)(row - 256) * DD);
    float x0 = src[t], x1 = src[t + 256];
    float s = x0 * x0 + x1 * x1;
    for (int o = 1; o < 64; o <<= 1) s += __shfl_xor(s, o);
    __shared__ float ws4[4];
    if ((t & 63) == 0) ws4[t >> 6] = s;
    __syncthreads();
    float r = rsqrtf(ws4[0] + ws4[1] + ws4[2] + ws4[3]);
    __bf16 a0 = (__bf16)(x0 * r), a1 = (__bf16)(x1 * r);
    // k-tiled: (row, d) -> At[(d>>5)*16384 + row*32 + (d&31)]
    At[(size_t)(t >> 5) * (BD * 32) + row * 32 + (t & 31)]         = a0;
    At[(size_t)((t + 256) >> 5) * (BD * 32) + row * 32 + (t & 31)] = a1;

    const int c = lab[row & 255];
    float w0 = (float)(__bf16)W[(size_t)c * DD + t];
    float w1 = (float)(__bf16)W[(size_t)c * DD + t + 256];
    float dot = (float)a0 * w0 + (float)a1 * w1;
    float wsq = w0 * w0 + w1 * w1;
    for (int o = 1; o < 64; o <<= 1) { dot += __shfl_xor(dot, o); wsq += __shfl_xor(wsq, o); }
    __shared__ float sd[4], sw[4];
    if ((t & 63) == 0) { sd[t >> 6] = dot; sw[t >> 6] = wsq; }
    __syncthreads();
    if (t == 0) {
        float D = sd[0] + sd[1] + sd[2] + sd[3];
        float Q = sw[0] + sw[1] + sw[2] + sw[3];
        float cs = D * rsqrtf(Q);
        float sn = sqrtf(fmaxf(0.f, fminf(1.f, 1.f - cs * cs)));
        float phi = cs * COS_M - sn * SIN_M;
        if (!(cs > TH_C)) phi = cs - MM_C;
        sphi[row] = S_SCALE * phi;
        scos[row] = S_SCALE * cs;
        sums[row] = 0.f;
    }
}

// ---------------- Kernel 2: MFMA GEMM, 512 rows x 64 cols / block, 8 waves ----------------
// 2 blocks/CU (72KB LDS), 16 waves/CU. One barrier per tile; ALL loads for future tiles
// issued at body top (max issue-to-drain distance under the barrier's vmcnt(0) drain):
//   glds A(kt+1) -> As[alt], raw B(kt+2) -> regs; consume B(kt+1)->Bs[alt] after MFMAs.
__global__ __launch_bounds__(512, 4) void k_gemm(const __bf16* __restrict__ At,
                                                 const float* __restrict__ W,
                                                 float* __restrict__ sums) {
    __shared__ __bf16 As[2][BD * 32];   // 2 x 32 KB
    __shared__ __bf16 Bs[2][64 * 32];   // 2 x 4 KB
    __shared__ float  csq[64];

    const int t = threadIdx.x;          // 0..511
    const int cb = blockIdx.x;
    const int wave = t >> 6, lane = t & 63, q = lane >> 4, m16 = lane & 15;

    // B staging: thread t -> col t>>3 (0..63), k-chunk (t&7)*4
    const int bcol = t >> 3, kc = t & 7;
    const int gc = cb * 64 + bcol;
    const float* wp = W + (size_t)(gc < CC ? gc : 0) * DD + kc * 4;

    f32x4 acc[4][4] = {};
    float sq = 0.f;

#define GLDS_TILE(kt, buf)                                                              \
    {                                                                                   \
        const char* gs = (const char*)At + (size_t)(kt) * 32768;                        \
        char* ls = (char*)(&As[buf][0]);                                                \
        _Pragma("unroll")                                                               \
        for (int c4 = 0; c4 < 4; ++c4)                                                  \
            __builtin_amdgcn_global_load_lds(                                           \
                (AS1 void*)(gs + (c4 * 512 + t) * 16),                                  \
                (AS3 void*)(ls + (c4 * 512 + wave * 64) * 16), 16, 0, 0);               \
    }

#define CVT_BS(buf, v)                                                                  \
    {                                                                                   \
        bf16x4 b = { (__bf16)v.x, (__bf16)v.y, (__bf16)v.z, (__bf16)v.w };              \
        float f0 = (float)b[0], f1 = (float)b[1], f2 = (float)b[2], f3 = (float)b[3];   \
        sq += f0 * f0 + f1 * f1 + f2 * f2 + f3 * f3;                                    \
        *(bf16x4*)(&Bs[buf][bcol * 32 + kc * 4]) = b;                                   \
    }

    // prologue: B(0)->Bs[0], A(0) glds, B(1) raw in flight
    {
        float4 b0 = *(const float4*)(wp);
        CVT_BS(0, b0);
        GLDS_TILE(0, 0);
    }
    float4 braw_cur = *(const float4*)(wp + 32);   // B(1)
    float4 braw_nxt;
    __syncthreads();

    #pragma unroll
    for (int kt = 0; kt < 16; ++kt) {
        const int cur = kt & 1;
        // top-of-body issues (max in-flight time before next barrier's drain)
        if (kt < 15) GLDS_TILE(kt + 1, 1 - cur);
        if (kt < 14) braw_nxt = *(const float4*)(wp + (kt + 2) * 32);

        // fragments + MFMA for tile kt
        bf16x8 af[4], bf[4];
        #pragma unroll
        for (int i = 0; i < 4; ++i)
            af[i] = *(const bf16x8*)(&As[cur][(wave * 64 + i * 16 + m16) * 32 + q * 8]);
        #pragma unroll
        for (int j = 0; j < 4; ++j)
            bf[j] = *(const bf16x8*)(&Bs[cur][(j * 16 + m16) * 32 + q * 8]);
        #pragma unroll
        for (int j = 0; j < 4; ++j)
            #pragma unroll
            for (int i = 0; i < 4; ++i)
                acc[i][j] = __builtin_amdgcn_mfma_f32_16x16x32_bf16(af[i], bf[j], acc[i][j], 0, 0, 0);

        if (kt < 15) {
            CVT_BS(1 - cur, braw_cur);    // B(kt+1), loaded one body ago
            braw_cur = braw_nxt;
        }
        __syncthreads();
    }
#undef GLDS_TILE
#undef CVT_BS

    // per-col sumsq: reduce over the 8 staging threads of each col (t&7)
    sq += __shfl_xor(sq, 1);
    sq += __shfl_xor(sq, 2);
    sq += __shfl_xor(sq, 4);
    if (kc == 0) csq[bcol] = sq;
    __syncthreads();

    // epilogue: cosine scale + exp + per-row reduce + atomicAdd
    const bool lastb = (cb == LASTB);
    float inv[4]; bool val[4];
    #pragma unroll
    for (int j = 0; j < 4; ++j) {
        int ct = j * 16 + m16;
        val[j] = (!lastb) || (ct < 32);   // last block: 32 valid cols
        inv[j] = rsqrtf(csq[ct]) * S_SCALE;
    }
    #pragma unroll
    for (int i = 0; i < 4; ++i) {
        #pragma unroll
        for (int r = 0; r < 4; ++r) {
            float e = 0.f;
            #pragma unroll
            for (int j = 0; j < 4; ++j)
                if (val[j]) e += __expf(acc[i][j][r] * inv[j]);
            e += __shfl_xor(e, 1);
            e += __shfl_xor(e, 2);
            e += __shfl_xor(e, 4);
            e += __shfl_xor(e, 8);
            if (m16 == 0) {
                int row = wave * 64 + i * 16 + q * 4 + r;
                atomicAdd(&sums[row], e);
            }
        }
    }
}

// ---------------- Kernel 3: final logsumexp + label correction + mean ----------------
__global__ __launch_bounds__(256) void k_final(const float* __restrict__ sums,
                                               const float* __restrict__ sphi,
                                               const float* __restrict__ scos,
                                               float* __restrict__ out) {
    const int t = threadIdx.x;
    float acc = 0.f;
    #pragma unroll
    for (int h = 0; h < 2; ++h) {
        int row = t + h * 256;
        float lse = logf(sums[row]);
        float sp = sphi[row], sc = scos[row];
        float corr = log1pf(__expf(sp - lse) - __expf(sc - lse));
        acc += lse + corr - sp;
    }
    for (int o = 1; o < 64; o <<= 1) acc += __shfl_xor(acc, o);
    __shared__ float ws4[4];
    if ((t & 63) == 0) ws4[t >> 6] = acc;
    __syncthreads();
    if (t == 0) out[0] = (ws4[0] + ws4[1] + ws4[2] + ws4[3]) * (1.0f / 512.0f);
}

extern "C" void kernel_launch(void* const* d_in, const int* in_sizes, int n_in,
                              void* d_out, int out_size, void* d_ws, size_t ws_size,
                              hipStream_t stream) {
    const float* img  = (const float*)d_in[0];
    const float* prof = (const float*)d_in[1];
    const float* W    = (const float*)d_in[2];
    const int*   lab  = (const int*)d_in[3];

    char* ws = (char*)d_ws;
    __bf16* At   = (__bf16*)ws;                 // 524288 B (k-tiled)
    float* sphi  = (float*)(ws + 524288);       // 2048 B
    float* scos  = (float*)(ws + 526336);       // 2048 B
    float* sums  = (float*)(ws + 528384);       // 2048 B

    k_prep<<<BD, 256, 0, stream>>>(img, prof, W, lab, At, sphi, scos, sums);
    k_gemm<<<NCB, 512, 0, stream>>>(At, W, sums);
    k_final<<<1, 256, 0, stream>>>(sums, sphi, scos, (float*)d_out);
}